// Round 1
// baseline (1267.451 us; speedup 1.0000x reference)
//
#include <hip/hip_runtime.h>
#include <math.h>

static constexpr int NN = 100000;   // nodes
static constexpr int NE = 3200000;  // edges
static constexpr int HO = 1024;     // head out
static constexpr int RPB = 98;      // rows per block in head matmul

// ---- init: zero deg/agg/ssum, pack x = [feat1, feat2] interleaved ----
__global__ void init_nodes_k(const float* __restrict__ f1, const float* __restrict__ f2,
                             float* __restrict__ deg, float* __restrict__ agg,
                             float* __restrict__ x, float* __restrict__ ssum) {
    int i = blockIdx.x * blockDim.x + threadIdx.x;
    if (i < NN) {
        deg[i] = 0.f;
        agg[2*i] = 0.f; agg[2*i+1] = 0.f;
        x[2*i]   = f1[i]; x[2*i+1] = f2[i];
        ssum[2*i] = 0.f; ssum[2*i+1] = 0.f;
    }
}

// ---- init head accumulators with bias (both features get +net_b) ----
__global__ void init_xacc_k(const float* __restrict__ nb, float* __restrict__ xacc) {
    int j = blockIdx.x * blockDim.x + threadIdx.x;
    if (j < HO) { xacc[j] = nb[j]; xacc[HO + j] = nb[j]; }
}

// ---- edge pass: gather x[src]*norm, scatter-add to agg[dst]; layer 0 also counts deg ----
template<int COUNT_DEG>
__global__ void edge_k(const int* __restrict__ src, const int* __restrict__ dst,
                       const float* __restrict__ norm, const float* __restrict__ x,
                       float* __restrict__ agg, float* __restrict__ deg) {
    int e = blockIdx.x * blockDim.x + threadIdx.x;
    if (e < NE) {
        int s = src[e], d = dst[e];
        float w = norm[e];
        float m0 = x[2*s]   * w;
        float m1 = x[2*s+1] * w;
        if (COUNT_DEG) atomicAdd(&deg[d], 1.0f);
        atomicAdd(&agg[2*d],   m0);
        atomicAdd(&agg[2*d+1], m1);
    }
}

// ---- node update: rst = (x + agg*inv_deg)*w + b; ssum += rst; x = relu(rst); re-zero agg ----
__global__ void node_k(const float* __restrict__ deg, float* __restrict__ agg,
                       float* __restrict__ x, float* __restrict__ ssum,
                       const float* __restrict__ gw, const float* __restrict__ gb, int l) {
    int i = blockIdx.x * blockDim.x + threadIdx.x;
    if (i < NN) {
        float inv = 1.0f / fmaxf(deg[i], 1.0f);
        float w = gw[l], b = gb[l];
#pragma unroll
        for (int f = 0; f < 2; ++f) {
            float a = agg[2*i+f] * inv;
            float r = (x[2*i+f] + a) * w + b;
            ssum[2*i+f] += r;
            x[2*i+f] = fmaxf(r, 0.f);
            agg[2*i+f] = 0.f;   // ready for next layer
        }
    }
}

// ---- head matmul: xacc[f][j] += sum_i (ssum[i,f]/3) * W[i,j], streamed over W ----
__global__ __launch_bounds__(256) void head_k(const float* __restrict__ ssum,
                                              const float* __restrict__ W,
                                              float* __restrict__ xacc) {
    __shared__ float sf0[RPB], sf1[RPB];
    int r0 = blockIdx.x * RPB;
    int r1 = r0 + RPB; if (r1 > NN) r1 = NN;
    int nr = r1 - r0;
    int t  = threadIdx.x;
    const float sc = (1.0f / 3.0f);   // mean over 3 layers
    for (int k = t; k < nr; k += 256) {
        sf0[k] = ssum[2*(r0+k)]   * sc;
        sf1[k] = ssum[2*(r0+k)+1] * sc;
    }
    __syncthreads();
    float4 a1 = make_float4(0.f,0.f,0.f,0.f);
    float4 a2 = make_float4(0.f,0.f,0.f,0.f);
    int j0 = t * 4;
    const float* Wp = W + (size_t)r0 * HO + j0;
    for (int k = 0; k < nr; ++k) {
        float4 w4 = *reinterpret_cast<const float4*>(Wp);
        Wp += HO;
        float f1 = sf0[k], f2 = sf1[k];
        a1.x = fmaf(f1, w4.x, a1.x); a1.y = fmaf(f1, w4.y, a1.y);
        a1.z = fmaf(f1, w4.z, a1.z); a1.w = fmaf(f1, w4.w, a1.w);
        a2.x = fmaf(f2, w4.x, a2.x); a2.y = fmaf(f2, w4.y, a2.y);
        a2.z = fmaf(f2, w4.z, a2.z); a2.w = fmaf(f2, w4.w, a2.w);
    }
    atomicAdd(&xacc[j0+0], a1.x); atomicAdd(&xacc[j0+1], a1.y);
    atomicAdd(&xacc[j0+2], a1.z); atomicAdd(&xacc[j0+3], a1.w);
    atomicAdd(&xacc[HO+j0+0], a2.x); atomicAdd(&xacc[HO+j0+1], a2.y);
    atomicAdd(&xacc[HO+j0+2], a2.z); atomicAdd(&xacc[HO+j0+3], a2.w);
}

// ---- final: sigmoid(sum_j x1[j]*x2[j]) ----
__global__ void final_k(const float* __restrict__ xacc, float* __restrict__ out) {
    __shared__ float red[256];
    int t = threadIdx.x;
    float v = 0.f;
    for (int j = t; j < HO; j += 256) v += xacc[j] * xacc[HO + j];
    red[t] = v;
    __syncthreads();
    for (int s = 128; s > 0; s >>= 1) {
        if (t < s) red[t] += red[t + s];
        __syncthreads();
    }
    if (t == 0) out[0] = 1.0f / (1.0f + expf(-red[0]));
}

extern "C" void kernel_launch(void* const* d_in, const int* in_sizes, int n_in,
                              void* d_out, int out_size, void* d_ws, size_t ws_size,
                              hipStream_t stream) {
    const float* feat1 = (const float*)d_in[0];
    const float* feat2 = (const float*)d_in[1];
    const float* norm  = (const float*)d_in[2];
    const int*   src   = (const int*)  d_in[3];
    const int*   dst   = (const int*)  d_in[4];
    const float* gin_w = (const float*)d_in[5];
    const float* gin_b = (const float*)d_in[6];
    const float* net_w = (const float*)d_in[7];
    const float* net_b = (const float*)d_in[8];
    float* out = (float*)d_out;

    float* ws   = (float*)d_ws;
    float* deg  = ws;            // NN
    float* agg  = ws + NN;       // 2*NN (interleaved f0,f1)
    float* x    = ws + 3*NN;     // 2*NN
    float* ssum = ws + 5*NN;     // 2*NN
    float* xacc = ws + 7*NN;     // 2*HO

    int ng = (NN + 255) / 256;
    int eg = (NE + 255) / 256;

    init_nodes_k<<<ng, 256, 0, stream>>>(feat1, feat2, deg, agg, x, ssum);
    init_xacc_k<<<(HO + 255) / 256, 256, 0, stream>>>(net_b, xacc);

    edge_k<1><<<eg, 256, 0, stream>>>(src, dst, norm, x, agg, deg);
    node_k<<<ng, 256, 0, stream>>>(deg, agg, x, ssum, gin_w, gin_b, 0);
    edge_k<0><<<eg, 256, 0, stream>>>(src, dst, norm, x, agg, deg);
    node_k<<<ng, 256, 0, stream>>>(deg, agg, x, ssum, gin_w, gin_b, 1);
    edge_k<0><<<eg, 256, 0, stream>>>(src, dst, norm, x, agg, deg);
    node_k<<<ng, 256, 0, stream>>>(deg, agg, x, ssum, gin_w, gin_b, 2);

    head_k<<<(NN + RPB - 1) / RPB, 256, 0, stream>>>(ssum, net_w, xacc);
    final_k<<<1, 256, 0, stream>>>(xacc, out);
}

// Round 2
// 361.990 us; speedup vs baseline: 3.5013x; 3.5013x over previous
//
#include <hip/hip_runtime.h>
#include <math.h>

static constexpr int NN  = 100000;    // nodes
static constexpr int NE  = 3200000;   // edges
static constexpr int HO  = 1024;      // head out
static constexpr int BSH = 5;         // 32 nodes per bucket
static constexpr int BMASK = 31;
static constexpr int NB  = 3125;      // buckets (3125*32 == 100000)
static constexpr int PB  = 512;       // partition blocks for count/scatter
static constexpr int CHUNK = NE / PB; // 6250 edges per partition block
static constexpr int RPB = 100;       // rows per head block
static constexpr int HB  = NN / RPB;  // 1000 head blocks

// ---- pack x = [feat1, feat2] interleaved ----
__global__ void init_k(const float* __restrict__ f1, const float* __restrict__ f2,
                       float* __restrict__ x0) {
    int i = blockIdx.x * 256 + threadIdx.x;
    if (i < NN) { x0[2*i] = f1[i]; x0[2*i+1] = f2[i]; }
}

// ---- K1: per-(bucket, block) edge counts via LDS histogram ----
__global__ __launch_bounds__(256) void count_k(const int* __restrict__ dst,
                                               int* __restrict__ counts) {
    __shared__ int hist[NB];
    for (int i = threadIdx.x; i < NB; i += 256) hist[i] = 0;
    __syncthreads();
    int base = blockIdx.x * CHUNK;
    for (int i = threadIdx.x; i < CHUNK; i += 256) {
        int d = dst[base + i];
        atomicAdd(&hist[d >> BSH], 1);
    }
    __syncthreads();
    for (int i = threadIdx.x; i < NB; i += 256) counts[i * PB + blockIdx.x] = hist[i];
}

// ---- K2a: bucket totals ----
__global__ __launch_bounds__(256) void bsum_k(const int* __restrict__ counts,
                                              int* __restrict__ bsum) {
    __shared__ int sh[256];
    int b = blockIdx.x, t = threadIdx.x;
    int v = counts[b * PB + t] + counts[b * PB + t + 256];
    sh[t] = v; __syncthreads();
    for (int s = 128; s > 0; s >>= 1) { if (t < s) sh[t] += sh[t + s]; __syncthreads(); }
    if (t == 0) bsum[b] = sh[0];
}

// ---- K2b: exclusive scan of bucket totals -> bucket base offsets ----
__global__ void scan_k(const int* __restrict__ bsum, int* __restrict__ bbase) {
    __shared__ int sh[256];
    __shared__ int carry;
    int t = threadIdx.x;
    if (t == 0) carry = 0;
    __syncthreads();
    for (int base = 0; base < NB; base += 256) {
        int i = base + t;
        int v = (i < NB) ? bsum[i] : 0;
        sh[t] = v; __syncthreads();
        for (int off = 1; off < 256; off <<= 1) {
            int tv = (t >= off) ? sh[t - off] : 0; __syncthreads();
            sh[t] += tv; __syncthreads();
        }
        int incl = sh[t], tot = sh[255];
        if (i < NB) bbase[i] = carry + incl - v;
        __syncthreads();
        if (t == 0) carry += tot;
        __syncthreads();
    }
    if (t == 0) bbase[NB] = carry;   // == NE
}

// ---- K2c: per-bucket exclusive scan over partition blocks (in place) ----
__global__ __launch_bounds__(256) void boffs_k(int* __restrict__ counts,
                                               const int* __restrict__ bbase) {
    __shared__ int sh[256];
    __shared__ int carry;
    int b = blockIdx.x, t = threadIdx.x;
    if (t == 0) carry = bbase[b];
    __syncthreads();
    for (int base = 0; base < PB; base += 256) {
        int v = counts[b * PB + base + t];
        sh[t] = v; __syncthreads();
        for (int off = 1; off < 256; off <<= 1) {
            int tv = (t >= off) ? sh[t - off] : 0; __syncthreads();
            sh[t] += tv; __syncthreads();
        }
        int incl = sh[t], tot = sh[255];
        counts[b * PB + base + t] = carry + incl - v;
        __syncthreads();
        if (t == 0) carry += tot;
        __syncthreads();
    }
}

// ---- K3: scatter edges into bucketed order; record = (src | (dst&31)<<17, norm) ----
__global__ __launch_bounds__(256) void scatter_k(const int* __restrict__ src,
                                                 const int* __restrict__ dst,
                                                 const float* __restrict__ norm,
                                                 const int* __restrict__ counts,
                                                 uint2* __restrict__ sorted) {
    __shared__ int cur[NB];
    int blk = blockIdx.x;
    for (int i = threadIdx.x; i < NB; i += 256) cur[i] = counts[i * PB + blk];
    __syncthreads();
    int base = blk * CHUNK;
    for (int i = threadIdx.x; i < CHUNK; i += 256) {
        int e = base + i;
        int d = dst[e], s = src[e];
        float w = norm[e];
        int b = d >> BSH;
        int pos = atomicAdd(&cur[b], 1);
        sorted[pos] = make_uint2((unsigned)s | ((unsigned)(d & BMASK) << 17),
                                 __float_as_uint(w));
    }
}

// ---- per-layer: bucket aggregation in LDS + fused node update (no global atomics) ----
template<int L0>
__global__ __launch_bounds__(256) void layer_k(const uint2* __restrict__ sorted,
                                               const int* __restrict__ bbase,
                                               const float* __restrict__ xin,
                                               float* __restrict__ xout,
                                               float* __restrict__ ssum,
                                               const float* __restrict__ gw,
                                               const float* __restrict__ gb, int l) {
    __shared__ float acc[64];
    __shared__ int cnt[32];
    int t = threadIdx.x, b = blockIdx.x;
    if (t < 64) acc[t] = 0.f;
    if (t < 32) cnt[t] = 0;
    __syncthreads();
    int s0 = bbase[b], s1 = bbase[b + 1];
    const float2* x2 = (const float2*)xin;
    for (int i = s0 + t; i < s1; i += 256) {
        uint2 r = sorted[i];
        int s  = r.x & 131071;
        int lo = (r.x >> 17) & 31;
        float w = __uint_as_float(r.y);
        float2 xx = x2[s];
        atomicAdd(&acc[2*lo],     xx.x * w);
        atomicAdd(&acc[2*lo + 1], xx.y * w);
        atomicAdd(&cnt[lo], 1);
    }
    __syncthreads();
    if (t < 64) {
        int lo = t >> 1, f = t & 1;
        int node = (b << BSH) + lo;
        float inv = 1.f / fmaxf((float)cnt[lo], 1.f);
        float w = gw[l], bb = gb[l];
        float r = (xin[(node << 1) + f] + acc[t] * inv) * w + bb;
        if (L0) ssum[(node << 1) + f] = r;
        else    ssum[(node << 1) + f] += r;
        xout[(node << 1) + f] = fmaxf(r, 0.f);
    }
}

// ---- head: per-block partial of [2,RPB] @ W[RPB,1024] ----
__global__ __launch_bounds__(256) void head_k(const float* __restrict__ ssum,
                                              const float* __restrict__ W,
                                              float* __restrict__ part) {
    __shared__ float sf0[RPB], sf1[RPB];
    int r0 = blockIdx.x * RPB;
    int t = threadIdx.x;
    const float sc = 1.0f / 3.0f;
    if (t < RPB) {
        sf0[t] = ssum[2*(r0+t)]   * sc;
        sf1[t] = ssum[2*(r0+t)+1] * sc;
    }
    __syncthreads();
    float4 a1 = make_float4(0.f,0.f,0.f,0.f);
    float4 a2 = make_float4(0.f,0.f,0.f,0.f);
    int j0 = t * 4;
    const float* Wp = W + (size_t)r0 * HO + j0;
    for (int k = 0; k < RPB; ++k) {
        float4 w4 = *reinterpret_cast<const float4*>(Wp);
        Wp += HO;
        float f1 = sf0[k], f2 = sf1[k];
        a1.x = fmaf(f1, w4.x, a1.x); a1.y = fmaf(f1, w4.y, a1.y);
        a1.z = fmaf(f1, w4.z, a1.z); a1.w = fmaf(f1, w4.w, a1.w);
        a2.x = fmaf(f2, w4.x, a2.x); a2.y = fmaf(f2, w4.y, a2.y);
        a2.z = fmaf(f2, w4.z, a2.z); a2.w = fmaf(f2, w4.w, a2.w);
    }
    float* pp = part + (size_t)blockIdx.x * 2048;
    pp[j0]   = a1.x; pp[j0+1] = a1.y; pp[j0+2] = a1.z; pp[j0+3] = a1.w;
    pp[1024+j0]   = a2.x; pp[1024+j0+1] = a2.y;
    pp[1024+j0+2] = a2.z; pp[1024+j0+3] = a2.w;
}

// ---- reduce partials + bias ----
__global__ void reduce_k(const float* __restrict__ part, const float* __restrict__ nb,
                         float* __restrict__ xacc) {
    int j = blockIdx.x * 256 + threadIdx.x;   // 0..2047
    float s = nb[j & 1023];
    for (int b = 0; b < HB; ++b) s += part[(size_t)b * 2048 + j];
    xacc[j] = s;
}

// ---- final: sigmoid(sum_j x1[j]*x2[j]) ----
__global__ void final_k(const float* __restrict__ xacc, float* __restrict__ out) {
    __shared__ float red[256];
    int t = threadIdx.x;
    float v = 0.f;
    for (int j = t; j < HO; j += 256) v += xacc[j] * xacc[HO + j];
    red[t] = v;
    __syncthreads();
    for (int s = 128; s > 0; s >>= 1) {
        if (t < s) red[t] += red[t + s];
        __syncthreads();
    }
    if (t == 0) out[0] = 1.0f / (1.0f + expf(-red[0]));
}

extern "C" void kernel_launch(void* const* d_in, const int* in_sizes, int n_in,
                              void* d_out, int out_size, void* d_ws, size_t ws_size,
                              hipStream_t stream) {
    const float* feat1 = (const float*)d_in[0];
    const float* feat2 = (const float*)d_in[1];
    const float* norm  = (const float*)d_in[2];
    const int*   src   = (const int*)  d_in[3];
    const int*   dst   = (const int*)  d_in[4];
    const float* gin_w = (const float*)d_in[5];
    const float* gin_b = (const float*)d_in[6];
    const float* net_w = (const float*)d_in[7];
    const float* net_b = (const float*)d_in[8];
    float* out = (float*)d_out;

    char* p = (char*)d_ws;
    uint2* sorted = (uint2*)p;                 p += (size_t)NE * 8;        // 25.6 MB
    float* part   = (float*)sorted;            // aliased: used only after layers
    int*   counts = (int*)p;                   p += (size_t)NB * PB * 4;   // 6.4 MB
    int*   bsum   = (int*)p;                   p += ((size_t)NB * 4 + 15) & ~15ull;
    int*   bbase  = (int*)p;                   p += ((size_t)(NB + 1) * 4 + 15) & ~15ull;
    float* x0     = (float*)p;                 p += (size_t)2 * NN * 4;
    float* x1     = (float*)p;                 p += (size_t)2 * NN * 4;
    float* ssum   = (float*)p;                 p += (size_t)2 * NN * 4;
    float* xacc   = (float*)p;                 p += (size_t)2 * HO * 4;

    init_k<<<(NN + 255) / 256, 256, 0, stream>>>(feat1, feat2, x0);
    count_k<<<PB, 256, 0, stream>>>(dst, counts);
    bsum_k<<<NB, 256, 0, stream>>>(counts, bsum);
    scan_k<<<1, 256, 0, stream>>>(bsum, bbase);
    boffs_k<<<NB, 256, 0, stream>>>(counts, bbase);
    scatter_k<<<PB, 256, 0, stream>>>(src, dst, norm, counts, sorted);

    layer_k<1><<<NB, 256, 0, stream>>>(sorted, bbase, x0, x1, ssum, gin_w, gin_b, 0);
    layer_k<0><<<NB, 256, 0, stream>>>(sorted, bbase, x1, x0, ssum, gin_w, gin_b, 1);
    layer_k<0><<<NB, 256, 0, stream>>>(sorted, bbase, x0, x1, ssum, gin_w, gin_b, 2);

    head_k<<<HB, 256, 0, stream>>>(ssum, net_w, part);
    reduce_k<<<8, 256, 0, stream>>>(part, net_b, xacc);
    final_k<<<1, 256, 0, stream>>>(xacc, out);
}

// Round 4
// 294.349 us; speedup vs baseline: 4.3059x; 1.2298x over previous
//
#include <hip/hip_runtime.h>
#include <math.h>

static constexpr int NN  = 100000;    // nodes
static constexpr int NE  = 3200000;   // edges
static constexpr int HO  = 1024;      // head out
static constexpr int BSH = 5;         // 32 nodes per bucket
static constexpr int BMASK = 31;
static constexpr int NB  = 3125;      // buckets (3125*32 == 100000)
static constexpr int PB  = 512;       // partition blocks for count/scatter
static constexpr int CHUNK = NE / PB; // 6250 edges per partition block
static constexpr int RPB = 100;       // rows per head block
static constexpr int HB  = NN / RPB;  // 1000 head blocks

typedef float f4v __attribute__((ext_vector_type(4)));   // native vector for nontemporal builtin

// ---- pack x = [feat1, feat2] interleaved ----
__global__ void init_k(const float* __restrict__ f1, const float* __restrict__ f2,
                       float2* __restrict__ x0) {
    int i = blockIdx.x * 256 + threadIdx.x;
    if (i < NN) x0[i] = make_float2(f1[i], f2[i]);
}

// ---- K1: per-(bucket, block) edge counts via LDS histogram ----
__global__ __launch_bounds__(256) void count_k(const int* __restrict__ dst,
                                               int* __restrict__ counts) {
    __shared__ int hist[NB];
    for (int i = threadIdx.x; i < NB; i += 256) hist[i] = 0;
    __syncthreads();
    int base = blockIdx.x * CHUNK;
    for (int i = threadIdx.x; i < CHUNK; i += 256) {
        int d = dst[base + i];
        atomicAdd(&hist[d >> BSH], 1);
    }
    __syncthreads();
    for (int i = threadIdx.x; i < NB; i += 256) counts[i * PB + blockIdx.x] = hist[i];
}

// ---- K2a: bucket totals ----
__global__ __launch_bounds__(256) void bsum_k(const int* __restrict__ counts,
                                              int* __restrict__ bsum) {
    __shared__ int sh[256];
    int b = blockIdx.x, t = threadIdx.x;
    int v = counts[b * PB + t] + counts[b * PB + t + 256];
    sh[t] = v; __syncthreads();
    for (int s = 128; s > 0; s >>= 1) { if (t < s) sh[t] += sh[t + s]; __syncthreads(); }
    if (t == 0) bsum[b] = sh[0];
}

// ---- K2b: exclusive scan of bucket totals (single pass, register-local) ----
__global__ __launch_bounds__(256) void scan_k(const int* __restrict__ bsum,
                                              int* __restrict__ bbase) {
    __shared__ int tot[256];
    constexpr int PER = (NB + 255) / 256;   // 13
    int t = threadIdx.x;
    int base = t * PER;
    int loc[PER];
    int s = 0;
    for (int k = 0; k < PER; ++k) {
        int i = base + k;
        int v = (i < NB) ? bsum[i] : 0;
        loc[k] = s; s += v;
    }
    tot[t] = s; __syncthreads();
    for (int off = 1; off < 256; off <<= 1) {
        int v = (t >= off) ? tot[t - off] : 0; __syncthreads();
        tot[t] += v; __syncthreads();
    }
    int carry = (t > 0) ? tot[t - 1] : 0;
    for (int k = 0; k < PER; ++k) {
        int i = base + k;
        if (i < NB) bbase[i] = carry + loc[k];
    }
    if (t == 0) bbase[NB] = NE;
}

// ---- K2c: per-bucket exclusive scan over partition blocks (in place) ----
__global__ __launch_bounds__(256) void boffs_k(int* __restrict__ counts,
                                               const int* __restrict__ bbase) {
    __shared__ int sh[256];
    __shared__ int carry;
    int b = blockIdx.x, t = threadIdx.x;
    if (t == 0) carry = bbase[b];
    __syncthreads();
    for (int base = 0; base < PB; base += 256) {
        int v = counts[b * PB + base + t];
        sh[t] = v; __syncthreads();
        for (int off = 1; off < 256; off <<= 1) {
            int tv = (t >= off) ? sh[t - off] : 0; __syncthreads();
            sh[t] += tv; __syncthreads();
        }
        int incl = sh[t], tot = sh[255];
        counts[b * PB + base + t] = carry + incl - v;
        __syncthreads();
        if (t == 0) carry += tot;
        __syncthreads();
    }
}

// ---- K3: scatter edges into bucket order; record = (src | (dst&31)<<17, norm) ----
__global__ __launch_bounds__(256) void scatter_k(const int* __restrict__ src,
                                                 const int* __restrict__ dst,
                                                 const float* __restrict__ norm,
                                                 const int* __restrict__ counts,
                                                 uint2* __restrict__ sorted) {
    __shared__ int cur[NB];
    int blk = blockIdx.x;
    for (int i = threadIdx.x; i < NB; i += 256) cur[i] = counts[i * PB + blk];
    __syncthreads();
    int base = blk * CHUNK;
    for (int i = threadIdx.x; i < CHUNK; i += 256) {
        int e = base + i;
        int d = dst[e], s = src[e];
        float w = norm[e];
        int b = d >> BSH;
        int pos = atomicAdd(&cur[b], 1);
        sorted[pos] = make_uint2((unsigned)s | ((unsigned)(d & BMASK) << 17),
                                 __float_as_uint(w));
    }
}

// ---- K4: within-bucket sort to node-level CSR; w pre-divided by deg ----
__global__ __launch_bounds__(256) void sort2_k(const uint2* __restrict__ sorted,
                                               const int* __restrict__ bbase,
                                               uint2* __restrict__ sorted2,
                                               int* __restrict__ nodeoff) {
    __shared__ int cnt[32];
    __shared__ int cur[32];
    __shared__ float inv[32];
    int b = blockIdx.x, t = threadIdx.x;
    if (t < 32) cnt[t] = 0;
    __syncthreads();
    int s0 = bbase[b], s1 = bbase[b + 1];
    for (int i = s0 + t; i < s1; i += 256) {
        int lo = (sorted[i].x >> 17) & BMASK;
        atomicAdd(&cnt[lo], 1);
    }
    __syncthreads();
    if (t == 0) {
        int pre = s0;
        for (int lo = 0; lo < 32; ++lo) {
            int c = cnt[lo];
            cur[lo] = pre;
            inv[lo] = 1.0f / fmaxf((float)c, 1.0f);
            nodeoff[(b << BSH) + lo] = pre;
            pre += c;
        }
    }
    if (b == 0 && t == 64) nodeoff[NN] = NE;
    __syncthreads();
    for (int i = s0 + t; i < s1; i += 256) {
        uint2 r = sorted[i];
        int lo = (r.x >> 17) & BMASK;
        int pos = atomicAdd(&cur[lo], 1);
        float w = __uint_as_float(r.y) * inv[lo];
        sorted2[pos] = make_uint2(r.x & 131071u, __float_as_uint(w));
    }
}

// ---- per-layer: thread-per-node CSR gather + fused node update (no atomics) ----
template<int L0>
__global__ __launch_bounds__(256) void layer_k(const uint2* __restrict__ s2,
                                               const int* __restrict__ noff,
                                               const float2* __restrict__ xin,
                                               float2* __restrict__ xout,
                                               float2* __restrict__ ssum,
                                               const float* __restrict__ gw,
                                               const float* __restrict__ gb, int l) {
    int node = blockIdx.x * 256 + threadIdx.x;
    if (node >= NN) return;
    int i0 = noff[node], i1 = noff[node + 1];
    float ax = 0.f, ay = 0.f;
    int i = i0;
    for (; i + 3 < i1; i += 4) {
        uint2 r0 = s2[i], r1 = s2[i+1], r2 = s2[i+2], r3 = s2[i+3];
        float2 x0 = xin[r0.x]; float w0 = __uint_as_float(r0.y);
        float2 x1 = xin[r1.x]; float w1 = __uint_as_float(r1.y);
        float2 x2 = xin[r2.x]; float w2 = __uint_as_float(r2.y);
        float2 x3 = xin[r3.x]; float w3 = __uint_as_float(r3.y);
        ax = fmaf(x0.x, w0, ax); ay = fmaf(x0.y, w0, ay);
        ax = fmaf(x1.x, w1, ax); ay = fmaf(x1.y, w1, ay);
        ax = fmaf(x2.x, w2, ax); ay = fmaf(x2.y, w2, ay);
        ax = fmaf(x3.x, w3, ax); ay = fmaf(x3.y, w3, ay);
    }
    for (; i < i1; ++i) {
        uint2 r = s2[i];
        float2 xx = xin[r.x]; float w = __uint_as_float(r.y);
        ax = fmaf(xx.x, w, ax); ay = fmaf(xx.y, w, ay);
    }
    float w = gw[l], bb = gb[l];
    float2 xv = xin[node];
    float rx = fmaf(xv.x + ax, w, bb);
    float ry = fmaf(xv.y + ay, w, bb);
    if (L0) ssum[node] = make_float2(rx, ry);
    else { float2 s = ssum[node]; ssum[node] = make_float2(s.x + rx, s.y + ry); }
    xout[node] = make_float2(fmaxf(rx, 0.f), fmaxf(ry, 0.f));
}

// ---- head: per-block partial of [2,RPB] @ W[RPB,1024] ----
__global__ __launch_bounds__(256) void head_k(const float2* __restrict__ ssum,
                                              const float* __restrict__ W,
                                              float* __restrict__ part) {
    __shared__ float sf0[RPB], sf1[RPB];
    int r0 = blockIdx.x * RPB;
    int t = threadIdx.x;
    const float sc = 1.0f / 3.0f;
    if (t < RPB) {
        float2 s = ssum[r0 + t];
        sf0[t] = s.x * sc;
        sf1[t] = s.y * sc;
    }
    __syncthreads();
    float ax1=0.f, ay1=0.f, az1=0.f, aw1=0.f;
    float ax2=0.f, ay2=0.f, az2=0.f, aw2=0.f;
    int j0 = t * 4;
    const f4v* Wp = reinterpret_cast<const f4v*>(W + (size_t)r0 * HO + j0);
#pragma unroll 4
    for (int k = 0; k < RPB; ++k) {
        f4v w4 = __builtin_nontemporal_load(Wp);
        Wp += HO / 4;
        float f1 = sf0[k], f2 = sf1[k];
        ax1 = fmaf(f1, w4.x, ax1); ay1 = fmaf(f1, w4.y, ay1);
        az1 = fmaf(f1, w4.z, az1); aw1 = fmaf(f1, w4.w, aw1);
        ax2 = fmaf(f2, w4.x, ax2); ay2 = fmaf(f2, w4.y, ay2);
        az2 = fmaf(f2, w4.z, az2); aw2 = fmaf(f2, w4.w, aw2);
    }
    float* pp = part + (size_t)blockIdx.x * 2048;
    pp[j0]   = ax1; pp[j0+1] = ay1; pp[j0+2] = az1; pp[j0+3] = aw1;
    pp[1024+j0]   = ax2; pp[1024+j0+1] = ay2;
    pp[1024+j0+2] = az2; pp[1024+j0+3] = aw2;
}

// ---- reduce partials + bias ----
__global__ void reduce_k(const float* __restrict__ part, const float* __restrict__ nb,
                         float* __restrict__ xacc) {
    int j = blockIdx.x * 256 + threadIdx.x;   // 0..2047
    float s = nb[j & 1023];
    for (int b = 0; b < HB; ++b) s += part[(size_t)b * 2048 + j];
    xacc[j] = s;
}

// ---- final: sigmoid(sum_j x1[j]*x2[j]) ----
__global__ void final_k(const float* __restrict__ xacc, float* __restrict__ out) {
    __shared__ float red[256];
    int t = threadIdx.x;
    float v = 0.f;
    for (int j = t; j < HO; j += 256) v += xacc[j] * xacc[HO + j];
    red[t] = v;
    __syncthreads();
    for (int s = 128; s > 0; s >>= 1) {
        if (t < s) red[t] += red[t + s];
        __syncthreads();
    }
    if (t == 0) out[0] = 1.0f / (1.0f + expf(-red[0]));
}

extern "C" void kernel_launch(void* const* d_in, const int* in_sizes, int n_in,
                              void* d_out, int out_size, void* d_ws, size_t ws_size,
                              hipStream_t stream) {
    const float* feat1 = (const float*)d_in[0];
    const float* feat2 = (const float*)d_in[1];
    const float* norm  = (const float*)d_in[2];
    const int*   src   = (const int*)  d_in[3];
    const int*   dst   = (const int*)  d_in[4];
    const float* gin_w = (const float*)d_in[5];
    const float* gin_b = (const float*)d_in[6];
    const float* net_w = (const float*)d_in[7];
    const float* net_b = (const float*)d_in[8];
    float* out = (float*)d_out;

    char* p = (char*)d_ws;
    uint2* sorted  = (uint2*)p;               p += (size_t)NE * 8;        // 25.6 MB
    float* part    = (float*)sorted;          // aliased: used only after layers
    uint2* sorted2 = (uint2*)p;               p += (size_t)NE * 8;        // 25.6 MB
    int*   counts  = (int*)p;                 p += (size_t)NB * PB * 4;   // 6.4 MB
    int*   bsum    = (int*)p;                 p += ((size_t)NB * 4 + 15) & ~15ull;
    int*   bbase   = (int*)p;                 p += ((size_t)(NB + 1) * 4 + 15) & ~15ull;
    int*   nodeoff = (int*)p;                 p += ((size_t)(NN + 1) * 4 + 15) & ~15ull;
    float2* x0     = (float2*)p;              p += (size_t)NN * 8;
    float2* x1     = (float2*)p;              p += (size_t)NN * 8;
    float2* ssum   = (float2*)p;              p += (size_t)NN * 8;
    float* xacc    = (float*)p;               p += (size_t)2 * HO * 4;

    int ng = (NN + 255) / 256;

    init_k<<<ng, 256, 0, stream>>>(feat1, feat2, x0);
    count_k<<<PB, 256, 0, stream>>>(dst, counts);
    bsum_k<<<NB, 256, 0, stream>>>(counts, bsum);
    scan_k<<<1, 256, 0, stream>>>(bsum, bbase);
    boffs_k<<<NB, 256, 0, stream>>>(counts, bbase);
    scatter_k<<<PB, 256, 0, stream>>>(src, dst, norm, counts, sorted);
    sort2_k<<<NB, 256, 0, stream>>>(sorted, bbase, sorted2, nodeoff);

    layer_k<1><<<ng, 256, 0, stream>>>(sorted2, nodeoff, x0, x1, ssum, gin_w, gin_b, 0);
    layer_k<0><<<ng, 256, 0, stream>>>(sorted2, nodeoff, x1, x0, ssum, gin_w, gin_b, 1);
    layer_k<0><<<ng, 256, 0, stream>>>(sorted2, nodeoff, x0, x1, ssum, gin_w, gin_b, 2);

    head_k<<<HB, 256, 0, stream>>>(ssum, net_w, part);
    reduce_k<<<8, 256, 0, stream>>>(part, net_b, xacc);
    final_k<<<1, 256, 0, stream>>>(xacc, out);
}

// Round 5
// 290.263 us; speedup vs baseline: 4.3666x; 1.0141x over previous
//
#include <hip/hip_runtime.h>
#include <math.h>

static constexpr int NN  = 100000;    // nodes
static constexpr int NE  = 3200000;   // edges
static constexpr int HO  = 1024;      // head out
static constexpr int BSH = 5;         // 32 nodes per bucket
static constexpr int BMASK = 31;
static constexpr int NB  = 3125;      // buckets (3125*32 == 100000)
static constexpr int NBP = NB + 1;    // loff row stride
static constexpr int PB  = 256;       // partition blocks
static constexpr int CHUNK = NE / PB; // 12500 edges per partition block
static constexpr int RPB = 100;       // rows per head block
static constexpr int HB  = NN / RPB;  // 1000 head blocks
static constexpr int CAP = 2048;      // max edges per bucket (avg 1024, +32 sigma)
static constexpr int PER = (NB + 255) / 256;  // 13

typedef float f4v __attribute__((ext_vector_type(4)));

// adjacent buckets -> same XCD (bijective, m204-style)
__device__ __forceinline__ int bucket_swz(int blk) {
    int x = blk & 7, g = blk >> 3;
    return (x < 5) ? x * 391 + g : 1955 + (x - 5) * 390 + g;
}

// ---- pack x = [feat1, feat2]; zero xacc ----
__global__ void init_k(const float* __restrict__ f1, const float* __restrict__ f2,
                       float2* __restrict__ x0, float* __restrict__ xacc) {
    int i = blockIdx.x * 256 + threadIdx.x;
    if (i < NN) x0[i] = make_float2(f1[i], f2[i]);
    if (i < 2 * HO) xacc[i] = 0.f;
}

// ---- phase A: fused histogram + local bucket-sort into OWN contiguous region ----
__global__ __launch_bounds__(256) void partA_k(const int* __restrict__ src,
                                               const int* __restrict__ dst,
                                               const float* __restrict__ norm,
                                               int* __restrict__ loffg,
                                               uint2* __restrict__ blocked) {
    __shared__ int hist[NB];
    __shared__ int scanbuf[256];
    int blk = blockIdx.x, t = threadIdx.x;
    for (int i = t; i < NB; i += 256) hist[i] = 0;
    __syncthreads();
    int base = blk * CHUNK;
    for (int i = t; i < CHUNK; i += 256)
        atomicAdd(&hist[dst[base + i] >> BSH], 1);
    __syncthreads();
    // exclusive scan of hist -> local offsets; export table; hist becomes cursor
    int loc[PER]; int s = 0;
    int b0 = t * PER;
    for (int k = 0; k < PER; ++k) {
        int i = b0 + k;
        int v = (i < NB) ? hist[i] : 0;
        loc[k] = s; s += v;
    }
    scanbuf[t] = s; __syncthreads();
    for (int off = 1; off < 256; off <<= 1) {
        int v = (t >= off) ? scanbuf[t - off] : 0; __syncthreads();
        scanbuf[t] += v; __syncthreads();
    }
    int carry = t ? scanbuf[t - 1] : 0;
    for (int k = 0; k < PER; ++k) {
        int i = b0 + k;
        if (i < NB) {
            int e = carry + loc[k];
            loffg[blk * NBP + i] = e;
            hist[i] = e;                 // cursor
        }
    }
    if (t == 0) loffg[blk * NBP + NB] = CHUNK;
    __syncthreads();
    // scatter into own region (dense, single-writer -> L2 absorbs)
    for (int i = t; i < CHUNK; i += 256) {
        int e = base + i;
        int d = dst[e];                  // L2-hot re-read
        int pos = atomicAdd(&hist[d >> BSH], 1);
        blocked[base + pos] = make_uint2((unsigned)src[e] | ((unsigned)(d & BMASK) << 17),
                                         __float_as_uint(norm[e]));
    }
}

// ---- bucket totals from loff diffs (coalesced across threads) ----
__global__ __launch_bounds__(256) void bsum_k(const int* __restrict__ loffg,
                                              int* __restrict__ bsum) {
    int b = blockIdx.x * 256 + threadIdx.x;
    if (b >= NB) return;
    int s = 0;
    for (int k = 0; k < PB; ++k)
        s += loffg[k * NBP + b + 1] - loffg[k * NBP + b];
    bsum[b] = s;
}

// ---- exclusive scan of bucket totals (single block, register-local) ----
__global__ __launch_bounds__(256) void scan_k(const int* __restrict__ bsum,
                                              int* __restrict__ bbase,
                                              int* __restrict__ nodeoff) {
    __shared__ int tot[256];
    int t = threadIdx.x;
    int base = t * PER;
    int loc[PER]; int s = 0;
    for (int k = 0; k < PER; ++k) {
        int i = base + k;
        int v = (i < NB) ? bsum[i] : 0;
        loc[k] = s; s += v;
    }
    tot[t] = s; __syncthreads();
    for (int off = 1; off < 256; off <<= 1) {
        int v = (t >= off) ? tot[t - off] : 0; __syncthreads();
        tot[t] += v; __syncthreads();
    }
    int carry = t ? tot[t - 1] : 0;
    for (int k = 0; k < PER; ++k) {
        int i = base + k;
        if (i < NB) bbase[i] = carry + loc[k];
    }
    if (t == 0) { bbase[NB] = NE; nodeoff[NN] = NE; }
}

// ---- phase B: per bucket, gather runs -> LDS, node-sort, stream out CSR ----
__global__ __launch_bounds__(256) void sortB_k(const uint2* __restrict__ blocked,
                                               const int* __restrict__ loffg,
                                               const int* __restrict__ bbase,
                                               uint2* __restrict__ sorted2,
                                               int* __restrict__ nodeoff) {
    __shared__ uint2 rec[CAP];
    __shared__ uint2 outb[CAP];
    __shared__ int runoff[256];
    __shared__ int cnt[32], cur[32], preoff[32];
    __shared__ float inv[32];
    int t = threadIdx.x;
    int b = bucket_swz(blockIdx.x);
    int o0 = loffg[t * NBP + b];
    int o1 = loffg[t * NBP + b + 1];
    int len = o1 - o0;
    if (t < 32) cnt[t] = 0;
    runoff[t] = len; __syncthreads();
    for (int off = 1; off < 256; off <<= 1) {
        int v = (t >= off) ? runoff[t - off] : 0; __syncthreads();
        runoff[t] += v; __syncthreads();
    }
    int start = runoff[t] - len;
    int total = runoff[255];
    if (total > CAP) total = CAP;           // safety clamp (never expected)
    const uint2* srcp = blocked + (size_t)t * CHUNK + o0;
    for (int j = 0; j < len; ++j) {
        int p = start + j;
        if (p < CAP) rec[p] = srcp[j];
    }
    __syncthreads();
    for (int i = t; i < total; i += 256)
        atomicAdd(&cnt[(rec[i].x >> 17) & BMASK], 1);
    __syncthreads();
    if (t == 0) {
        int pre = 0;
        for (int lo = 0; lo < 32; ++lo) {
            int c = cnt[lo];
            preoff[lo] = pre; cur[lo] = pre;
            inv[lo] = 1.0f / fmaxf((float)c, 1.0f);
            pre += c;
        }
    }
    __syncthreads();
    for (int i = t; i < total; i += 256) {
        uint2 r = rec[i];
        int lo = (r.x >> 17) & BMASK;
        int pos = atomicAdd(&cur[lo], 1);
        outb[pos] = make_uint2(r.x & 131071u,
                               __float_as_uint(__uint_as_float(r.y) * inv[lo]));
    }
    __syncthreads();
    int s0 = bbase[b];
    for (int i = t; i < total; i += 256) sorted2[s0 + i] = outb[i];
    if (t < 32) nodeoff[(b << BSH) + t] = s0 + preoff[t];
}

// ---- per-layer: thread-per-node CSR gather + fused node update (no atomics) ----
template<int L0>
__global__ __launch_bounds__(256) void layer_k(const uint2* __restrict__ s2,
                                               const int* __restrict__ noff,
                                               const float2* __restrict__ xin,
                                               float2* __restrict__ xout,
                                               float2* __restrict__ ssum,
                                               const float* __restrict__ gw,
                                               const float* __restrict__ gb, int l) {
    int node = blockIdx.x * 256 + threadIdx.x;
    if (node >= NN) return;
    int i0 = noff[node], i1 = noff[node + 1];
    float ax = 0.f, ay = 0.f;
    int i = i0;
    for (; i + 3 < i1; i += 4) {
        uint2 r0 = s2[i], r1 = s2[i+1], r2 = s2[i+2], r3 = s2[i+3];
        float2 x0 = xin[r0.x]; float w0 = __uint_as_float(r0.y);
        float2 x1 = xin[r1.x]; float w1 = __uint_as_float(r1.y);
        float2 x2 = xin[r2.x]; float w2 = __uint_as_float(r2.y);
        float2 x3 = xin[r3.x]; float w3 = __uint_as_float(r3.y);
        ax = fmaf(x0.x, w0, ax); ay = fmaf(x0.y, w0, ay);
        ax = fmaf(x1.x, w1, ax); ay = fmaf(x1.y, w1, ay);
        ax = fmaf(x2.x, w2, ax); ay = fmaf(x2.y, w2, ay);
        ax = fmaf(x3.x, w3, ax); ay = fmaf(x3.y, w3, ay);
    }
    for (; i < i1; ++i) {
        uint2 r = s2[i];
        float2 xx = xin[r.x]; float w = __uint_as_float(r.y);
        ax = fmaf(xx.x, w, ax); ay = fmaf(xx.y, w, ay);
    }
    float w = gw[l], bb = gb[l];
    float2 xv = xin[node];
    float rx = fmaf(xv.x + ax, w, bb);
    float ry = fmaf(xv.y + ay, w, bb);
    if (L0) ssum[node] = make_float2(rx, ry);
    else { float2 s = ssum[node]; ssum[node] = make_float2(s.x + rx, s.y + ry); }
    xout[node] = make_float2(fmaxf(rx, 0.f), fmaxf(ry, 0.f));
}

// ---- head: per-block partial of [2,RPB] @ W[RPB,1024] ----
__global__ __launch_bounds__(256) void head_k(const float2* __restrict__ ssum,
                                              const float* __restrict__ W,
                                              float* __restrict__ part) {
    __shared__ float sf0[RPB], sf1[RPB];
    int r0 = blockIdx.x * RPB;
    int t = threadIdx.x;
    const float sc = 1.0f / 3.0f;
    if (t < RPB) {
        float2 s = ssum[r0 + t];
        sf0[t] = s.x * sc;
        sf1[t] = s.y * sc;
    }
    __syncthreads();
    float ax1=0.f, ay1=0.f, az1=0.f, aw1=0.f;
    float ax2=0.f, ay2=0.f, az2=0.f, aw2=0.f;
    int j0 = t * 4;
    const f4v* Wp = reinterpret_cast<const f4v*>(W + (size_t)r0 * HO + j0);
#pragma unroll 4
    for (int k = 0; k < RPB; ++k) {
        f4v w4 = __builtin_nontemporal_load(Wp);
        Wp += HO / 4;
        float f1 = sf0[k], f2 = sf1[k];
        ax1 = fmaf(f1, w4.x, ax1); ay1 = fmaf(f1, w4.y, ay1);
        az1 = fmaf(f1, w4.z, az1); aw1 = fmaf(f1, w4.w, aw1);
        ax2 = fmaf(f2, w4.x, ax2); ay2 = fmaf(f2, w4.y, ay2);
        az2 = fmaf(f2, w4.z, az2); aw2 = fmaf(f2, w4.w, aw2);
    }
    float* pp = part + (size_t)blockIdx.x * 2048;
    pp[j0]   = ax1; pp[j0+1] = ay1; pp[j0+2] = az1; pp[j0+3] = aw1;
    pp[1024+j0]   = ax2; pp[1024+j0+1] = ay2;
    pp[1024+j0+2] = az2; pp[1024+j0+3] = aw2;
}

// ---- reduce partials (64 blocks, 8-way split of rows, atomics into xacc) ----
__global__ __launch_bounds__(256) void reduce_k(const float* __restrict__ part,
                                                float* __restrict__ xacc) {
    int gid = blockIdx.x * 256 + threadIdx.x;   // 0..16383
    int j = gid & 2047;
    int seg = gid >> 11;                        // 0..7
    float s = 0.f;
    int b0 = seg * (HB / 8), b1 = b0 + HB / 8;
    for (int b = b0; b < b1; ++b) s += part[(size_t)b * 2048 + j];
    atomicAdd(&xacc[j], s);
}

// ---- final: sigmoid(sum_j (x1+b)(x2+b)) ----
__global__ void final_k(const float* __restrict__ xacc, const float* __restrict__ nb,
                        float* __restrict__ out) {
    __shared__ float red[256];
    int t = threadIdx.x;
    float v = 0.f;
    for (int j = t; j < HO; j += 256)
        v += (xacc[j] + nb[j]) * (xacc[HO + j] + nb[j]);
    red[t] = v;
    __syncthreads();
    for (int s = 128; s > 0; s >>= 1) {
        if (t < s) red[t] += red[t + s];
        __syncthreads();
    }
    if (t == 0) out[0] = 1.0f / (1.0f + expf(-red[0]));
}

extern "C" void kernel_launch(void* const* d_in, const int* in_sizes, int n_in,
                              void* d_out, int out_size, void* d_ws, size_t ws_size,
                              hipStream_t stream) {
    const float* feat1 = (const float*)d_in[0];
    const float* feat2 = (const float*)d_in[1];
    const float* norm  = (const float*)d_in[2];
    const int*   src   = (const int*)  d_in[3];
    const int*   dst   = (const int*)  d_in[4];
    const float* gin_w = (const float*)d_in[5];
    const float* gin_b = (const float*)d_in[6];
    const float* net_w = (const float*)d_in[7];
    const float* net_b = (const float*)d_in[8];
    float* out = (float*)d_out;

    char* p = (char*)d_ws;
    uint2* blocked = (uint2*)p;               p += (size_t)NE * 8;          // 25.6 MB
    float* part    = (float*)blocked;         // alias: used only after sortB
    uint2* sorted2 = (uint2*)p;               p += (size_t)NE * 8;          // 25.6 MB
    int*   loffg   = (int*)p;                 p += (size_t)PB * NBP * 4;    // 3.2 MB
    int*   bsum    = (int*)p;                 p += ((size_t)NB * 4 + 15) & ~15ull;
    int*   bbase   = (int*)p;                 p += ((size_t)(NB + 1) * 4 + 15) & ~15ull;
    int*   nodeoff = (int*)p;                 p += ((size_t)(NN + 1) * 4 + 15) & ~15ull;
    float2* x0     = (float2*)p;              p += (size_t)NN * 8;
    float2* x1     = (float2*)p;              p += (size_t)NN * 8;
    float2* ssum   = (float2*)p;              p += (size_t)NN * 8;
    float* xacc    = (float*)p;               p += (size_t)2 * HO * 4;

    int ng = (NN + 255) / 256;

    init_k<<<ng, 256, 0, stream>>>(feat1, feat2, x0, xacc);
    partA_k<<<PB, 256, 0, stream>>>(src, dst, norm, loffg, blocked);
    bsum_k<<<(NB + 255) / 256, 256, 0, stream>>>(loffg, bsum);
    scan_k<<<1, 256, 0, stream>>>(bsum, bbase, nodeoff);
    sortB_k<<<NB, 256, 0, stream>>>(blocked, loffg, bbase, sorted2, nodeoff);

    layer_k<1><<<ng, 256, 0, stream>>>(sorted2, nodeoff, x0, x1, ssum, gin_w, gin_b, 0);
    layer_k<0><<<ng, 256, 0, stream>>>(sorted2, nodeoff, x1, x0, ssum, gin_w, gin_b, 1);
    layer_k<0><<<ng, 256, 0, stream>>>(sorted2, nodeoff, x0, x1, ssum, gin_w, gin_b, 2);

    head_k<<<HB, 256, 0, stream>>>(ssum, net_w, part);
    reduce_k<<<64, 256, 0, stream>>>(part, xacc);
    final_k<<<1, 256, 0, stream>>>(xacc, net_b, out);
}

// Round 6
// 232.762 us; speedup vs baseline: 5.4453x; 1.2470x over previous
//
#include <hip/hip_runtime.h>
#include <math.h>

static constexpr int NN  = 100000;    // nodes
static constexpr int NE  = 3200000;   // edges
static constexpr int HO  = 1024;      // head out
static constexpr int BSH = 5;         // 32 nodes per bucket
static constexpr int BMASK = 31;
static constexpr int NB  = 3125;      // buckets (3125*32 == 100000)
static constexpr int NBP = NB + 1;    // loffg row stride
static constexpr int PB  = 256;       // partition blocks
static constexpr int CHUNK = NE / PB; // 12500 edges per partition block
static constexpr int AT  = 512;       // partA threads
static constexpr int PER_A = (NB + AT - 1) / AT;  // 7
static constexpr int RPB = 100;       // rows per head block
static constexpr int HB  = NN / RPB;  // 1000 head blocks
static constexpr int CAP = 2048;      // max edges per bucket (avg 1024, +32 sigma)
static constexpr int BT  = 49;        // bucket tiles (49*64 >= 3125)

typedef float f4v __attribute__((ext_vector_type(4)));

// adjacent buckets -> same XCD (bijective: 5 groups of 391, 3 of 390)
__device__ __forceinline__ int bucket_swz(int blk) {
    int x = blk & 7, g = blk >> 3;
    return (x < 5) ? x * 391 + g : 1955 + (x - 5) * 390 + g;
}

// ---- pack x = [feat1, feat2]; zero xacc; set nodeoff sentinel ----
__global__ void init_k(const float* __restrict__ f1, const float* __restrict__ f2,
                       float2* __restrict__ x0, float* __restrict__ xacc,
                       int* __restrict__ nodeoff) {
    int i = blockIdx.x * 256 + threadIdx.x;
    if (i < NN) x0[i] = make_float2(f1[i], f2[i]);
    if (i < 2 * HO) xacc[i] = 0.f;
    if (i == 0) nodeoff[NN] = NE;
}

// ---- phase A: fused histogram + local bucket-sort into OWN contiguous region ----
__global__ __launch_bounds__(AT) void partA_k(const int* __restrict__ src,
                                              const int* __restrict__ dst,
                                              const float* __restrict__ norm,
                                              int* __restrict__ loffg,
                                              uint2* __restrict__ blocked) {
    __shared__ int hist[NB];
    __shared__ int scanbuf[AT];
    int blk = blockIdx.x, t = threadIdx.x;
    for (int i = t; i < NB; i += AT) hist[i] = 0;
    __syncthreads();
    int base = blk * CHUNK;
    for (int i = t; i < CHUNK; i += AT)
        atomicAdd(&hist[dst[base + i] >> BSH], 1);
    __syncthreads();
    // exclusive scan of hist -> local offsets; export; hist becomes cursor
    int loc[PER_A]; int s = 0;
    int b0 = t * PER_A;
    for (int k = 0; k < PER_A; ++k) {
        int i = b0 + k;
        int v = (i < NB) ? hist[i] : 0;
        loc[k] = s; s += v;
    }
    scanbuf[t] = s; __syncthreads();
    for (int off = 1; off < AT; off <<= 1) {
        int v = (t >= off) ? scanbuf[t - off] : 0; __syncthreads();
        scanbuf[t] += v; __syncthreads();
    }
    int carry = t ? scanbuf[t - 1] : 0;
    for (int k = 0; k < PER_A; ++k) {
        int i = b0 + k;
        if (i < NB) {
            int e = carry + loc[k];
            loffg[blk * NBP + i] = e;
            hist[i] = e;                 // cursor
        }
    }
    __syncthreads();
    for (int i = t; i < CHUNK; i += AT) {
        int e = base + i;
        int d = dst[e];                  // L2-hot re-read
        int pos = atomicAdd(&hist[d >> BSH], 1);
        blocked[base + pos] = make_uint2((unsigned)src[e] | ((unsigned)(d & BMASK) << 17),
                                         __float_as_uint(norm[e]));
    }
}

// ---- tiled transpose: loffg[k][b] -> loffT[b][k] (both sides coalesced) ----
__global__ __launch_bounds__(256) void transT_k(const int* __restrict__ loffg,
                                                int* __restrict__ loffT) {
    __shared__ int tile[64][65];
    int bx = blockIdx.x % BT;          // bucket tile
    int ky = blockIdx.x / BT;          // k tile (0..3)
    int tx = threadIdx.x & 63, ty = threadIdx.x >> 6;
    int b = bx * 64 + tx;
#pragma unroll
    for (int j = 0; j < 16; ++j) {
        int k = ky * 64 + ty + j * 4;
        tile[ty + j * 4][tx] = (b < NB) ? loffg[k * NBP + b] : 0;
    }
    __syncthreads();
#pragma unroll
    for (int j = 0; j < 16; ++j) {
        int row = ty + j * 4;
        int bb = bx * 64 + row;
        if (bb < NB) loffT[bb * PB + ky * 64 + tx] = tile[tx][row];
    }
}

// ---- phase B: per bucket, gather runs -> LDS, node-sort, scatter CSR out ----
// bucket base = sum_t loffT[b][t] (free: we load those values anyway)
__global__ __launch_bounds__(256) void sortB_k(const uint2* __restrict__ blocked,
                                               const int* __restrict__ loffT,
                                               uint2* __restrict__ sorted2,
                                               int* __restrict__ nodeoff) {
    __shared__ uint2 rec[CAP];
    __shared__ int runoff[256];
    __shared__ int cnt[32], cur[32], preoff[32];
    __shared__ float inv[32];
    __shared__ int s0sh;
    int t = threadIdx.x;
    int b = bucket_swz(blockIdx.x);
    int o0 = loffT[b * PB + t];
    int o1 = (b == NB - 1) ? CHUNK : loffT[(b + 1) * PB + t];
    int len = o1 - o0;
    if (t == 0) s0sh = 0;
    if (t < 32) cnt[t] = 0;
    runoff[t] = len;
    __syncthreads();
    atomicAdd(&s0sh, o0);              // bucket global base accumulates here
    for (int off = 1; off < 256; off <<= 1) {
        int v = (t >= off) ? runoff[t - off] : 0; __syncthreads();
        runoff[t] += v; __syncthreads();
    }
    int start = runoff[t] - len;
    int total = runoff[255];
    if (total > CAP) total = CAP;      // safety clamp (never expected)
    const uint2* srcp = blocked + (size_t)t * CHUNK + o0;
    for (int j = 0; j < len; ++j) {
        int p = start + j;
        if (p < CAP) rec[p] = srcp[j];
    }
    __syncthreads();
    for (int i = t; i < total; i += 256)
        atomicAdd(&cnt[(rec[i].x >> 17) & BMASK], 1);
    __syncthreads();
    if (t == 0) {
        int pre = 0;
        for (int lo = 0; lo < 32; ++lo) {
            int c = cnt[lo];
            preoff[lo] = pre; cur[lo] = pre;
            inv[lo] = 1.0f / fmaxf((float)c, 1.0f);
            pre += c;
        }
    }
    __syncthreads();
    int s0 = s0sh;
    for (int i = t; i < total; i += 256) {
        uint2 r = rec[i];
        int lo = (r.x >> 17) & BMASK;
        int pos = atomicAdd(&cur[lo], 1);
        sorted2[(size_t)s0 + pos] = make_uint2(r.x & 131071u,
                               __float_as_uint(__uint_as_float(r.y) * inv[lo]));
    }
    if (t < 32) nodeoff[(b << BSH) + t] = s0 + preoff[t];
}

// ---- per-layer: 8 lanes per node, coalesced CSR reads, shfl combine ----
template<int L0>
__global__ __launch_bounds__(256) void layer_k(const uint2* __restrict__ s2,
                                               const int* __restrict__ noff,
                                               const float2* __restrict__ xin,
                                               float2* __restrict__ xout,
                                               float2* __restrict__ ssum,
                                               const float* __restrict__ gw,
                                               const float* __restrict__ gb, int l) {
    int gid = blockIdx.x * 256 + threadIdx.x;
    int node = gid >> 3, r = gid & 7;
    if (node >= NN) return;
    int i0 = noff[node], i1 = noff[node + 1];
    float ax = 0.f, ay = 0.f;
    for (int i = i0 + r; i < i1; i += 8) {
        uint2 rec = s2[i];
        float2 xx = xin[rec.x];
        float w = __uint_as_float(rec.y);
        ax = fmaf(xx.x, w, ax); ay = fmaf(xx.y, w, ay);
    }
#pragma unroll
    for (int off = 1; off < 8; off <<= 1) {
        ax += __shfl_xor(ax, off, 64);
        ay += __shfl_xor(ay, off, 64);
    }
    if (r == 0) {
        float w = gw[l], bb = gb[l];
        float2 xv = xin[node];
        float rx = fmaf(xv.x + ax, w, bb);
        float ry = fmaf(xv.y + ay, w, bb);
        if (L0) ssum[node] = make_float2(rx, ry);
        else { float2 s = ssum[node]; ssum[node] = make_float2(s.x + rx, s.y + ry); }
        xout[node] = make_float2(fmaxf(rx, 0.f), fmaxf(ry, 0.f));
    }
}

// ---- head: per-block partial of [2,RPB] @ W[RPB,1024] ----
__global__ __launch_bounds__(256) void head_k(const float2* __restrict__ ssum,
                                              const float* __restrict__ W,
                                              float* __restrict__ part) {
    __shared__ float sf0[RPB], sf1[RPB];
    int r0 = blockIdx.x * RPB;
    int t = threadIdx.x;
    const float sc = 1.0f / 3.0f;
    if (t < RPB) {
        float2 s = ssum[r0 + t];
        sf0[t] = s.x * sc;
        sf1[t] = s.y * sc;
    }
    __syncthreads();
    float ax1=0.f, ay1=0.f, az1=0.f, aw1=0.f;
    float ax2=0.f, ay2=0.f, az2=0.f, aw2=0.f;
    int j0 = t * 4;
    const f4v* Wp = reinterpret_cast<const f4v*>(W + (size_t)r0 * HO + j0);
#pragma unroll 4
    for (int k = 0; k < RPB; ++k) {
        f4v w4 = __builtin_nontemporal_load(Wp);
        Wp += HO / 4;
        float f1 = sf0[k], f2 = sf1[k];
        ax1 = fmaf(f1, w4.x, ax1); ay1 = fmaf(f1, w4.y, ay1);
        az1 = fmaf(f1, w4.z, az1); aw1 = fmaf(f1, w4.w, aw1);
        ax2 = fmaf(f2, w4.x, ax2); ay2 = fmaf(f2, w4.y, ay2);
        az2 = fmaf(f2, w4.z, az2); aw2 = fmaf(f2, w4.w, aw2);
    }
    float* pp = part + (size_t)blockIdx.x * 2048;
    pp[j0]   = ax1; pp[j0+1] = ay1; pp[j0+2] = az1; pp[j0+3] = aw1;
    pp[1024+j0]   = ax2; pp[1024+j0+1] = ay2;
    pp[1024+j0+2] = az2; pp[1024+j0+3] = aw2;
}

// ---- reduce partials (256 blocks, 32-way row split, atomics into xacc) ----
__global__ __launch_bounds__(256) void reduce_k(const float* __restrict__ part,
                                                float* __restrict__ xacc) {
    int gid = blockIdx.x * 256 + threadIdx.x;   // 0..65535
    int j = gid & 2047;
    int seg = gid >> 11;                        // 0..31
    int b0 = (seg * HB) >> 5, b1 = ((seg + 1) * HB) >> 5;
    float s = 0.f;
    for (int b = b0; b < b1; ++b) s += part[(size_t)b * 2048 + j];
    atomicAdd(&xacc[j], s);
}

// ---- final: sigmoid(sum_j (x1+b)(x2+b)) ----
__global__ void final_k(const float* __restrict__ xacc, const float* __restrict__ nb,
                        float* __restrict__ out) {
    __shared__ float red[256];
    int t = threadIdx.x;
    float v = 0.f;
    for (int j = t; j < HO; j += 256)
        v += (xacc[j] + nb[j]) * (xacc[HO + j] + nb[j]);
    red[t] = v;
    __syncthreads();
    for (int s = 128; s > 0; s >>= 1) {
        if (t < s) red[t] += red[t + s];
        __syncthreads();
    }
    if (t == 0) out[0] = 1.0f / (1.0f + expf(-red[0]));
}

extern "C" void kernel_launch(void* const* d_in, const int* in_sizes, int n_in,
                              void* d_out, int out_size, void* d_ws, size_t ws_size,
                              hipStream_t stream) {
    const float* feat1 = (const float*)d_in[0];
    const float* feat2 = (const float*)d_in[1];
    const float* norm  = (const float*)d_in[2];
    const int*   src   = (const int*)  d_in[3];
    const int*   dst   = (const int*)  d_in[4];
    const float* gin_w = (const float*)d_in[5];
    const float* gin_b = (const float*)d_in[6];
    const float* net_w = (const float*)d_in[7];
    const float* net_b = (const float*)d_in[8];
    float* out = (float*)d_out;

    char* p = (char*)d_ws;
    uint2* blocked = (uint2*)p;               p += (size_t)NE * 8;          // 25.6 MB
    float* part    = (float*)blocked;         // alias: used only after sortB
    uint2* sorted2 = (uint2*)p;               p += (size_t)NE * 8;          // 25.6 MB
    int*   loffg   = (int*)p;                 p += (size_t)PB * NBP * 4;    // 3.2 MB
    int*   loffT   = (int*)p;                 p += (size_t)NB * PB * 4;     // 3.2 MB
    int*   nodeoff = (int*)p;                 p += ((size_t)(NN + 1) * 4 + 15) & ~15ull;
    float2* x0     = (float2*)p;              p += (size_t)NN * 8;
    float2* x1     = (float2*)p;              p += (size_t)NN * 8;
    float2* ssum   = (float2*)p;              p += (size_t)NN * 8;
    float* xacc    = (float*)p;               p += (size_t)2 * HO * 4;

    int ng = (NN + 255) / 256;
    int lg = (NN * 8 + 255) / 256;            // 3125 blocks for layers

    init_k<<<ng, 256, 0, stream>>>(feat1, feat2, x0, xacc, nodeoff);
    partA_k<<<PB, AT, 0, stream>>>(src, dst, norm, loffg, blocked);
    transT_k<<<BT * 4, 256, 0, stream>>>(loffg, loffT);
    sortB_k<<<NB, 256, 0, stream>>>(blocked, loffT, sorted2, nodeoff);

    layer_k<1><<<lg, 256, 0, stream>>>(sorted2, nodeoff, x0, x1, ssum, gin_w, gin_b, 0);
    layer_k<0><<<lg, 256, 0, stream>>>(sorted2, nodeoff, x1, x0, ssum, gin_w, gin_b, 1);
    layer_k<0><<<lg, 256, 0, stream>>>(sorted2, nodeoff, x0, x1, ssum, gin_w, gin_b, 2);

    head_k<<<HB, 256, 0, stream>>>(ssum, net_w, part);
    reduce_k<<<256, 256, 0, stream>>>(part, xacc);
    final_k<<<1, 256, 0, stream>>>(xacc, net_b, out);
}

// Round 7
// 226.825 us; speedup vs baseline: 5.5878x; 1.0262x over previous
//
#include <hip/hip_runtime.h>
#include <math.h>

static constexpr int NN  = 100000;    // nodes
static constexpr int NE  = 3200000;   // edges
static constexpr int HO  = 1024;      // head out
static constexpr int BSH = 5;         // 32 nodes per bucket
static constexpr int BMASK = 31;
static constexpr int NB  = 3125;      // buckets (3125*32 == 100000)
static constexpr int NBP = NB + 1;    // loffg row stride
static constexpr int PB  = 256;       // partition blocks
static constexpr int CHUNK = NE / PB; // 12500 edges per partition block
static constexpr int AT  = 512;       // partA threads
static constexpr int PER_A = (NB + AT - 1) / AT;  // 7
static constexpr int RPB = 50;        // rows per head block
static constexpr int HB  = NN / RPB;  // 2000 head blocks (all co-resident)
static constexpr int CAP = 2048;      // max edges per bucket (avg 1024, +32 sigma)
static constexpr int BT  = 49;        // bucket tiles (49*64 >= 3125)

typedef float f4v __attribute__((ext_vector_type(4)));

// adjacent buckets -> same XCD (bijective: 5 groups of 391, 3 of 390)
__device__ __forceinline__ int bucket_swz(int blk) {
    int x = blk & 7, g = blk >> 3;
    return (x < 5) ? x * 391 + g : 1955 + (x - 5) * 390 + g;
}

// ---- phase A (fused init): histogram + local bucket-sort into own region ----
__global__ __launch_bounds__(AT) void partA_k(const float* __restrict__ f1,
                                              const float* __restrict__ f2,
                                              const int* __restrict__ src,
                                              const int* __restrict__ dst,
                                              const float* __restrict__ norm,
                                              int* __restrict__ loffg,
                                              uint2* __restrict__ blocked,
                                              float2* __restrict__ x0,
                                              float* __restrict__ xacc,
                                              int* __restrict__ nodeoff) {
    __shared__ int hist[NB];
    __shared__ int wt[8];
    int blk = blockIdx.x, t = threadIdx.x;
    int lane = t & 63, w = t >> 6;
    // fused init (grid covers 131072 >= NN)
    int gi = blk * AT + t;
    if (gi < NN) x0[gi] = make_float2(f1[gi], f2[gi]);
    if (blk == 0) {
        for (int i = t; i < 2 * HO; i += AT) xacc[i] = 0.f;
        if (t == 0) nodeoff[NN] = NE;
    }
    for (int i = t; i < NB; i += AT) hist[i] = 0;
    __syncthreads();
    int base = blk * CHUNK;
    for (int i = t; i < CHUNK; i += AT)
        atomicAdd(&hist[dst[base + i] >> BSH], 1);
    __syncthreads();
    // per-thread exclusive scan over its 7 buckets, then wave scan + cross-wave
    int loc[PER_A]; int s = 0;
    int b0 = t * PER_A;
#pragma unroll
    for (int k = 0; k < PER_A; ++k) {
        int i = b0 + k;
        int v = (i < NB) ? hist[i] : 0;
        loc[k] = s; s += v;
    }
    int incl = s;
#pragma unroll
    for (int off = 1; off < 64; off <<= 1) {
        int v = __shfl_up(incl, off, 64);
        if (lane >= off) incl += v;
    }
    if (lane == 63) wt[w] = incl;
    __syncthreads();
    int wpre = 0;
#pragma unroll
    for (int k = 0; k < 8; ++k) if (k < w) wpre += wt[k];
    int carry = wpre + incl - s;
#pragma unroll
    for (int k = 0; k < PER_A; ++k) {
        int i = b0 + k;
        if (i < NB) {
            int e = carry + loc[k];
            loffg[blk * NBP + i] = e;
            hist[i] = e;                 // becomes cursor
        }
    }
    __syncthreads();
    for (int i = t; i < CHUNK; i += AT) {
        int e = base + i;
        int d = dst[e];                  // L2-hot re-read
        int pos = atomicAdd(&hist[d >> BSH], 1);
        blocked[base + pos] = make_uint2((unsigned)src[e] | ((unsigned)(d & BMASK) << 17),
                                         __float_as_uint(norm[e]));
    }
}

// ---- tiled transpose: loffg[k][b] -> loffT[b][k] (both sides coalesced) ----
__global__ __launch_bounds__(256) void transT_k(const int* __restrict__ loffg,
                                                int* __restrict__ loffT) {
    __shared__ int tile[64][65];
    int bx = blockIdx.x % BT;
    int ky = blockIdx.x / BT;
    int tx = threadIdx.x & 63, ty = threadIdx.x >> 6;
    int b = bx * 64 + tx;
#pragma unroll
    for (int j = 0; j < 16; ++j) {
        int k = ky * 64 + ty + j * 4;
        tile[ty + j * 4][tx] = (b < NB) ? loffg[k * NBP + b] : 0;
    }
    __syncthreads();
#pragma unroll
    for (int j = 0; j < 16; ++j) {
        int row = ty + j * 4;
        int bb = bx * 64 + row;
        if (bb < NB) loffT[bb * PB + ky * 64 + tx] = tile[tx][row];
    }
}

// ---- phase B: per bucket, batched run gather -> LDS, node-sort, scatter out ----
__global__ __launch_bounds__(256) void sortB_k(const uint2* __restrict__ blocked,
                                               const int* __restrict__ loffT,
                                               uint2* __restrict__ sorted2,
                                               int* __restrict__ nodeoff) {
    __shared__ uint2 rec[CAP];
    __shared__ int wtot[4], wsum[4];
    __shared__ int cnt[32], curs[32];
    __shared__ float inv[32];
    int t = threadIdx.x;
    int lane = t & 63, w = t >> 6;
    int b = bucket_swz(blockIdx.x);
    int o0 = loffT[b * PB + t];
    int o1 = (b == NB - 1) ? CHUNK : loffT[(b + 1) * PB + t];
    int len = o1 - o0;
    if (t < 32) cnt[t] = 0;
    // wave inclusive scan of len; wave sum of o0
    int incl = len;
#pragma unroll
    for (int off = 1; off < 64; off <<= 1) {
        int v = __shfl_up(incl, off, 64);
        if (lane >= off) incl += v;
    }
    int os = o0;
#pragma unroll
    for (int off = 32; off; off >>= 1) os += __shfl_xor(os, off, 64);
    if (lane == 63) wtot[w] = incl;
    if (lane == 0)  wsum[w] = os;
    __syncthreads();
    int wpre = 0, total = 0, s0 = 0;
#pragma unroll
    for (int k = 0; k < 4; ++k) {
        int tv = wtot[k];
        if (k < w) wpre += tv;
        total += tv; s0 += wsum[k];
    }
    int start = wpre + incl - len;
    if (total > CAP) total = CAP;        // safety clamp (never expected)
    // batched gather: 8 address-clamped loads issued together, rare tail
    {
        int lm = (len > 0) ? len - 1 : 0;
        const uint2* srcq = blocked + (size_t)t * CHUNK + o0;
        uint2 q0 = srcq[0];
        uint2 q1 = srcq[lm < 1 ? lm : 1];
        uint2 q2 = srcq[lm < 2 ? lm : 2];
        uint2 q3 = srcq[lm < 3 ? lm : 3];
        uint2 q4 = srcq[lm < 4 ? lm : 4];
        uint2 q5 = srcq[lm < 5 ? lm : 5];
        uint2 q6 = srcq[lm < 6 ? lm : 6];
        uint2 q7 = srcq[lm < 7 ? lm : 7];
        if (len > 0 && start + 0 < CAP) rec[start + 0] = q0;
        if (len > 1 && start + 1 < CAP) rec[start + 1] = q1;
        if (len > 2 && start + 2 < CAP) rec[start + 2] = q2;
        if (len > 3 && start + 3 < CAP) rec[start + 3] = q3;
        if (len > 4 && start + 4 < CAP) rec[start + 4] = q4;
        if (len > 5 && start + 5 < CAP) rec[start + 5] = q5;
        if (len > 6 && start + 6 < CAP) rec[start + 6] = q6;
        if (len > 7 && start + 7 < CAP) rec[start + 7] = q7;
        for (int j = 8; j < len; ++j)
            if (start + j < CAP) rec[start + j] = srcq[j];
    }
    __syncthreads();
    for (int i = t; i < total; i += 256)
        atomicAdd(&cnt[(rec[i].x >> 17) & BMASK], 1);
    __syncthreads();
    if (t < 32) {
        int c = cnt[t];
        int ic = c;
#pragma unroll
        for (int off = 1; off < 32; off <<= 1) {
            int v = __shfl_up(ic, off, 32);
            if (t >= off) ic += v;
        }
        curs[t] = ic - c;
        inv[t] = 1.0f / fmaxf((float)c, 1.0f);
        nodeoff[(b << BSH) + t] = s0 + ic - c;
    }
    __syncthreads();
    for (int i = t; i < total; i += 256) {
        uint2 r = rec[i];
        int lo = (r.x >> 17) & BMASK;
        int pos = atomicAdd(&curs[lo], 1);
        sorted2[(size_t)s0 + pos] = make_uint2(r.x & 131071u,
                               __float_as_uint(__uint_as_float(r.y) * inv[lo]));
    }
}

// ---- per-layer: 8 lanes/node, batched record+gather loads, shfl combine ----
template<int L0>
__global__ __launch_bounds__(256) void layer_k(const uint2* __restrict__ s2,
                                               const int* __restrict__ noff,
                                               const float2* __restrict__ xin,
                                               float2* __restrict__ xout,
                                               float2* __restrict__ ssum,
                                               const float* __restrict__ gw,
                                               const float* __restrict__ gb, int l) {
    int gid = blockIdx.x * 256 + threadIdx.x;
    int node = gid >> 3, r = gid & 7;
    if (node >= NN) return;
    int i0 = noff[node], i1 = noff[node + 1];
    float ax = 0.f, ay = 0.f;
    int i = i0 + r;
    while (i + 24 < i1) {            // full batch of 4 (deg=32 -> exactly one)
        uint2 a0 = s2[i], a1 = s2[i + 8], a2 = s2[i + 16], a3 = s2[i + 24];
        float2 xa = xin[a0.x], xb = xin[a1.x], xc = xin[a2.x], xd = xin[a3.x];
        ax = fmaf(xa.x, __uint_as_float(a0.y), ax); ay = fmaf(xa.y, __uint_as_float(a0.y), ay);
        ax = fmaf(xb.x, __uint_as_float(a1.y), ax); ay = fmaf(xb.y, __uint_as_float(a1.y), ay);
        ax = fmaf(xc.x, __uint_as_float(a2.y), ax); ay = fmaf(xc.y, __uint_as_float(a2.y), ay);
        ax = fmaf(xd.x, __uint_as_float(a3.y), ax); ay = fmaf(xd.y, __uint_as_float(a3.y), ay);
        i += 32;
    }
    for (; i < i1; i += 8) {
        uint2 a = s2[i];
        float2 xx = xin[a.x];
        float wv = __uint_as_float(a.y);
        ax = fmaf(xx.x, wv, ax); ay = fmaf(xx.y, wv, ay);
    }
#pragma unroll
    for (int off = 1; off < 8; off <<= 1) {
        ax += __shfl_xor(ax, off, 64);
        ay += __shfl_xor(ay, off, 64);
    }
    if (r == 0) {
        float wv = gw[l], bb = gb[l];
        float2 xv = xin[node];
        float rx = fmaf(xv.x + ax, wv, bb);
        float ry = fmaf(xv.y + ay, wv, bb);
        if (L0) ssum[node] = make_float2(rx, ry);
        else { float2 s = ssum[node]; ssum[node] = make_float2(s.x + rx, s.y + ry); }
        xout[node] = make_float2(fmaxf(rx, 0.f), fmaxf(ry, 0.f));
    }
}

// ---- head: per-block partial of [2,RPB] @ W[RPB,1024] ----
__global__ __launch_bounds__(256) void head_k(const float2* __restrict__ ssum,
                                              const float* __restrict__ W,
                                              float* __restrict__ part) {
    __shared__ float sf0[RPB], sf1[RPB];
    int r0 = blockIdx.x * RPB;
    int t = threadIdx.x;
    const float sc = 1.0f / 3.0f;
    if (t < RPB) {
        float2 s = ssum[r0 + t];
        sf0[t] = s.x * sc;
        sf1[t] = s.y * sc;
    }
    __syncthreads();
    float ax1=0.f, ay1=0.f, az1=0.f, aw1=0.f;
    float ax2=0.f, ay2=0.f, az2=0.f, aw2=0.f;
    int j0 = t * 4;
    const f4v* Wp = reinterpret_cast<const f4v*>(W + (size_t)r0 * HO + j0);
#pragma unroll 5
    for (int k = 0; k < RPB; ++k) {
        f4v w4 = __builtin_nontemporal_load(Wp);
        Wp += HO / 4;
        float f1 = sf0[k], f2 = sf1[k];
        ax1 = fmaf(f1, w4.x, ax1); ay1 = fmaf(f1, w4.y, ay1);
        az1 = fmaf(f1, w4.z, az1); aw1 = fmaf(f1, w4.w, aw1);
        ax2 = fmaf(f2, w4.x, ax2); ay2 = fmaf(f2, w4.y, ay2);
        az2 = fmaf(f2, w4.z, az2); aw2 = fmaf(f2, w4.w, aw2);
    }
    float* pp = part + (size_t)blockIdx.x * 2048;
    pp[j0]   = ax1; pp[j0+1] = ay1; pp[j0+2] = az1; pp[j0+3] = aw1;
    pp[1024+j0]   = ax2; pp[1024+j0+1] = ay2;
    pp[1024+j0+2] = az2; pp[1024+j0+3] = aw2;
}

// ---- reduce partials (256 blocks, 32-way row split, atomics into xacc) ----
__global__ __launch_bounds__(256) void reduce_k(const float* __restrict__ part,
                                                float* __restrict__ xacc) {
    int gid = blockIdx.x * 256 + threadIdx.x;   // 0..65535
    int j = gid & 2047;
    int seg = gid >> 11;                        // 0..31
    int b0 = (seg * HB) >> 5, b1 = ((seg + 1) * HB) >> 5;
    float s = 0.f;
    for (int b = b0; b < b1; ++b) s += part[(size_t)b * 2048 + j];
    atomicAdd(&xacc[j], s);
}

// ---- final: sigmoid(sum_j (x1+b)(x2+b)) ----
__global__ void final_k(const float* __restrict__ xacc, const float* __restrict__ nb,
                        float* __restrict__ out) {
    __shared__ float red[256];
    int t = threadIdx.x;
    float v = 0.f;
    for (int j = t; j < HO; j += 256)
        v += (xacc[j] + nb[j]) * (xacc[HO + j] + nb[j]);
    red[t] = v;
    __syncthreads();
    for (int s = 128; s > 0; s >>= 1) {
        if (t < s) red[t] += red[t + s];
        __syncthreads();
    }
    if (t == 0) out[0] = 1.0f / (1.0f + expf(-red[0]));
}

extern "C" void kernel_launch(void* const* d_in, const int* in_sizes, int n_in,
                              void* d_out, int out_size, void* d_ws, size_t ws_size,
                              hipStream_t stream) {
    const float* feat1 = (const float*)d_in[0];
    const float* feat2 = (const float*)d_in[1];
    const float* norm  = (const float*)d_in[2];
    const int*   src   = (const int*)  d_in[3];
    const int*   dst   = (const int*)  d_in[4];
    const float* gin_w = (const float*)d_in[5];
    const float* gin_b = (const float*)d_in[6];
    const float* net_w = (const float*)d_in[7];
    const float* net_b = (const float*)d_in[8];
    float* out = (float*)d_out;

    char* p = (char*)d_ws;
    uint2* blocked = (uint2*)p;               p += (size_t)NE * 8;          // 25.6 MB
    float* part    = (float*)blocked;         // alias: used only after sortB
    uint2* sorted2 = (uint2*)p;               p += (size_t)NE * 8;          // 25.6 MB
    int*   loffg   = (int*)p;                 p += (size_t)PB * NBP * 4;    // 3.2 MB
    int*   loffT   = (int*)p;                 p += (size_t)NB * PB * 4;     // 3.2 MB
    int*   nodeoff = (int*)p;                 p += ((size_t)(NN + 1) * 4 + 15) & ~15ull;
    float2* x0     = (float2*)p;              p += (size_t)NN * 8;
    float2* x1     = (float2*)p;              p += (size_t)NN * 8;
    float2* ssum   = (float2*)p;              p += (size_t)NN * 8;
    float* xacc    = (float*)p;               p += (size_t)2 * HO * 4;

    int lg = (NN * 8 + 255) / 256;            // 3125 blocks for layers

    partA_k<<<PB, AT, 0, stream>>>(feat1, feat2, src, dst, norm, loffg, blocked,
                                   x0, xacc, nodeoff);
    transT_k<<<BT * 4, 256, 0, stream>>>(loffg, loffT);
    sortB_k<<<NB, 256, 0, stream>>>(blocked, loffT, sorted2, nodeoff);

    layer_k<1><<<lg, 256, 0, stream>>>(sorted2, nodeoff, x0, x1, ssum, gin_w, gin_b, 0);
    layer_k<0><<<lg, 256, 0, stream>>>(sorted2, nodeoff, x1, x0, ssum, gin_w, gin_b, 1);
    layer_k<0><<<lg, 256, 0, stream>>>(sorted2, nodeoff, x0, x1, ssum, gin_w, gin_b, 2);

    head_k<<<HB, 256, 0, stream>>>(ssum, net_w, part);
    reduce_k<<<256, 256, 0, stream>>>(part, xacc);
    final_k<<<1, 256, 0, stream>>>(xacc, net_b, out);
}